// Round 2
// baseline (1025.258 us; speedup 1.0000x reference)
//
#include <hip/hip_runtime.h>

// Multi-level hash encoding, LDS-staged: one block covers CHUNK points for all
// 16 levels in 16 phases. Each phase stages the level's full table (<=128 KB)
// into LDS, then gathers 8 trilinear corners per point from LDS.
// Results are accumulated in registers and stored coalesced at the end.

#define B_POINTS (1 << 20)
#define NL 16
#define TAB_STRIDE (2 * (16384 + 1))   // floats per level in emb (incl. sentinel row)
#define TPB 1024
#define PPT 2                          // points per thread
#define CHUNK (TPB * PPT)              // 2048 points per block

__global__ __launch_bounds__(TPB, 1)
void hashenc_lds(const float* __restrict__ x,
                 const float* __restrict__ emb,
                 float* __restrict__ out)
{
    // floor(16 * gf^l), gf = float32 exp chain (rounds above 2^(1/3))
    constexpr int   RES_[NL]  = {16, 20, 25, 32, 40, 50, 64, 80,
                                 101, 128, 161, 203, 256, 322, 406, 512};
    constexpr float HALF_[NL] = {8.f, 10.f, 12.5f, 16.f, 20.f, 25.f, 32.f, 40.f,
                                 50.5f, 64.f, 80.5f, 101.5f, 128.f, 161.f, 203.f, 256.f};
    constexpr int   NLE_[NL]  = {4096, 8000, 15625, 16384, 16384, 16384, 16384, 16384,
                                 16384, 16384, 16384, 16384, 16384, 16384, 16384, 16384};

    extern __shared__ float2 lds[];    // 16384 entries = 128 KB

    const int  t    = threadIdx.x;
    const long base = (long)blockIdx.x * CHUNK;

    // Load this thread's PPT points (x is read exactly once per point, whole run)
    float px[PPT][3];
#pragma unroll
    for (int pp = 0; pp < PPT; ++pp) {
        const long p = base + t + (long)pp * TPB;
        px[pp][0] = x[p * 3 + 0];
        px[pp][1] = x[p * 3 + 1];
        px[pp][2] = x[p * 3 + 2];
    }

    float res[PPT][NL][2];

#pragma unroll
    for (int l = 0; l < NL; ++l) {
        const int   R      = RES_[l];
        const float half   = HALF_[l];
        const int   nle    = NLE_[l];
        const bool  direct = (l < 3);

        if (l) __syncthreads();        // previous phase's LDS reads must finish
        const float2* __restrict__ tab = (const float2*)(emb + (size_t)l * TAB_STRIDE);
        for (int i = t; i < nle; i += TPB)
            lds[i] = tab[i];           // coalesced 8 B/lane from L2-resident table
        __syncthreads();

#pragma unroll
        for (int pp = 0; pp < PPT; ++pp) {
            const float xs0 = (px[pp][0] + 1.0f) * half - 0.5f;
            const float xs1 = (px[pp][1] + 1.0f) * half - 0.5f;
            const float xs2 = (px[pp][2] + 1.0f) * half - 0.5f;
            const float fl0 = floorf(xs0), fl1 = floorf(xs1), fl2 = floorf(xs2);
            const float f0 = xs0 - fl0, f1 = xs1 - fl1, f2 = xs2 - fl2;
            const float g0 = 1.0f - f0, g1 = 1.0f - f1, g2 = 1.0f - f2;
            const int i0 = (int)fl0, i1 = (int)fl1, i2 = (int)fl2;

            // per-dim validity for offset 0 / 1
            const bool va0 = (i0 >= 0) & (i0 < R), vb0 = (i0 + 1 >= 0) & (i0 + 1 < R);
            const bool va1 = (i1 >= 0) & (i1 < R), vb1 = (i1 + 1 >= 0) & (i1 + 1 < R);
            const bool va2 = (i2 >= 0) & (i2 < R), vb2 = (i2 + 1 >= 0) & (i2 + 1 < R);

            // hash partials (4 muls per point-level instead of 16)
            const unsigned hy0 = (unsigned)i1 * 2654435761u;
            const unsigned hy1 = (unsigned)(i1 + 1) * 2654435761u;
            const unsigned hz0 = (unsigned)i2 * 805459861u;
            const unsigned hz1 = (unsigned)(i2 + 1) * 805459861u;

            float a0 = 0.0f, a1 = 0.0f;
#pragma unroll
            for (int k = 0; k < 8; ++k) {
                const int o0 = (k >> 2) & 1, o1 = (k >> 1) & 1, o2 = k & 1;
                const int c0 = i0 + o0, c1 = i1 + o1, c2 = i2 + o2;
                float w = (o0 ? f0 : g0) * (o1 ? f1 : g1) * (o2 ? f2 : g2);
                const bool valid = (o0 ? vb0 : va0) & (o1 ? vb1 : va1) & (o2 ? vb2 : va2);
                int id;
                if (direct) {
                    id = (c0 * R + c1) * R + c2;
                } else {
                    id = (int)(((unsigned)c0 ^ (o1 ? hy1 : hy0) ^ (o2 ? hz1 : hz0)) & 16383u);
                }
                id = valid ? id : 0;       // keep LDS read in-bounds
                w  = valid ? w  : 0.0f;    // sentinel row is zero -> contribute 0
                const float2 e = lds[id];
                a0 = fmaf(e.x, w, a0);
                a1 = fmaf(e.y, w, a1);
            }
            res[pp][l][0] = a0;
            res[pp][l][1] = a1;
        }
    }

    // Final store: 8 x float4 per point (per-lane 128 B contiguous; lines are
    // fully written by 4 temporally-adjacent stores of the same wave -> merges in L2)
#pragma unroll
    for (int pp = 0; pp < PPT; ++pp) {
        const long p = base + t + (long)pp * TPB;
        float4* o4 = (float4*)(out + p * 32);
#pragma unroll
        for (int j = 0; j < 8; ++j)
            o4[j] = make_float4(res[pp][2 * j][0],     res[pp][2 * j][1],
                                res[pp][2 * j + 1][0], res[pp][2 * j + 1][1]);
    }
}

extern "C" void kernel_launch(void* const* d_in, const int* in_sizes, int n_in,
                              void* d_out, int out_size, void* d_ws, size_t ws_size,
                              hipStream_t stream) {
    const float* x   = (const float*)d_in[0];   // (B, 3) f32
    const float* emb = (const float*)d_in[1];   // (16, 16385, 2) f32
    float* out = (float*)d_out;                 // (B, 16, 2) f32

    const int nblocks = B_POINTS / CHUNK;       // 512
    hashenc_lds<<<nblocks, TPB, 16384 * sizeof(float2), stream>>>(x, emb, out);
}

// Round 4
// 966.309 us; speedup vs baseline: 1.0610x; 1.0610x over previous
//
#include <hip/hip_runtime.h>

// Multi-level hash encoding, LDS-staged, v2b.
// One block = 2048 points x 16 levels in 16 phases; each phase stages the
// level's table (<=128 KB) into LDS, gathers 8 trilinear corners from LDS.
// Results held in registers; final store goes through an LDS transpose so
// global stores are lane-contiguous float4 (nontemporal, keeps tables in L2).

#define B_POINTS (1 << 20)
#define NL 16
#define TAB_STRIDE (2 * (16384 + 1))   // floats per level in emb (incl. sentinel row)
#define TPB 1024
#define PPT 2
#define CHUNK (TPB * PPT)              // 2048 points per block

typedef float vf4 __attribute__((ext_vector_type(4)));   // native vec for nt builtins

__global__ __launch_bounds__(TPB, 4)
void hashenc_lds2(const float* __restrict__ x,
                  const float* __restrict__ emb,
                  float* __restrict__ out)
{
    // floor(16 * gf^l), gf = float32 exp chain (rounds above 2^(1/3))
    constexpr int   RES_[NL]  = {16, 20, 25, 32, 40, 50, 64, 80,
                                 101, 128, 161, 203, 256, 322, 406, 512};
    constexpr float HALF_[NL] = {8.f, 10.f, 12.5f, 16.f, 20.f, 25.f, 32.f, 40.f,
                                 50.5f, 64.f, 80.5f, 101.5f, 128.f, 161.f, 203.f, 256.f};
    constexpr int   NLE_[NL]  = {4096, 8000, 15625, 16384, 16384, 16384, 16384, 16384,
                                 16384, 16384, 16384, 16384, 16384, 16384, 16384, 16384};

    extern __shared__ float lds_raw[];           // 128 KB
    float2* __restrict__ lds = (float2*)lds_raw;

    const int  t    = threadIdx.x;
    const long base = (long)blockIdx.x * CHUNK;

    // x: read once per point, stream (nt) so it doesn't evict tables from L2
    float px[PPT][3];
#pragma unroll
    for (int pp = 0; pp < PPT; ++pp) {
        const float* xp = x + (base + t + (long)pp * TPB) * 3;
        px[pp][0] = __builtin_nontemporal_load(xp + 0);
        px[pp][1] = __builtin_nontemporal_load(xp + 1);
        px[pp][2] = __builtin_nontemporal_load(xp + 2);
    }

    float res[PPT][NL][2];

#pragma unroll
    for (int l = 0; l < NL; ++l) {
        const int   R      = RES_[l];
        const float half   = HALF_[l];
        const int   nle    = NLE_[l];
        const bool  direct = (l < 3);

        if (l) __syncthreads();                  // previous phase's LDS reads done
        {   // stage table (float2: level base is only 8 B aligned for odd l)
            const float2* __restrict__ tab = (const float2*)(emb + (size_t)l * TAB_STRIDE);
            for (int i = t; i < nle; i += TPB)
                lds[i] = tab[i];                 // coalesced, L2-resident after first touch
        }
        __syncthreads();

#pragma unroll
        for (int pp = 0; pp < PPT; ++pp) {
            const float xs0 = (px[pp][0] + 1.0f) * half - 0.5f;
            const float xs1 = (px[pp][1] + 1.0f) * half - 0.5f;
            const float xs2 = (px[pp][2] + 1.0f) * half - 0.5f;
            const float fl0 = floorf(xs0), fl1 = floorf(xs1), fl2 = floorf(xs2);
            const float f0 = xs0 - fl0, f1 = xs1 - fl1, f2 = xs2 - fl2;
            const float g0 = 1.0f - f0, g1 = 1.0f - f1, g2 = 1.0f - f2;
            const int i0 = (int)fl0, i1 = (int)fl1, i2 = (int)fl2;

            const bool va0 = (i0 >= 0) & (i0 < R), wb0 = (i0 + 1 >= 0) & (i0 + 1 < R);
            const bool va1 = (i1 >= 0) & (i1 < R), wb1 = (i1 + 1 >= 0) & (i1 + 1 < R);
            const bool va2 = (i2 >= 0) & (i2 < R), wb2 = (i2 + 1 >= 0) & (i2 + 1 < R);

            const unsigned hy0 = (unsigned)i1 * 2654435761u;
            const unsigned hy1 = (unsigned)(i1 + 1) * 2654435761u;
            const unsigned hz0 = (unsigned)i2 * 805459861u;
            const unsigned hz1 = (unsigned)(i2 + 1) * 805459861u;

            float a0 = 0.0f, a1 = 0.0f;
#pragma unroll
            for (int k = 0; k < 8; ++k) {
                const int o0 = (k >> 2) & 1, o1 = (k >> 1) & 1, o2 = k & 1;
                const int c0 = i0 + o0, c1 = i1 + o1, c2 = i2 + o2;
                float w = (o0 ? f0 : g0) * (o1 ? f1 : g1) * (o2 ? f2 : g2);
                const bool valid = (o0 ? wb0 : va0) & (o1 ? wb1 : va1) & (o2 ? wb2 : va2);
                int id;
                if (direct) {
                    id = (c0 * R + c1) * R + c2;
                } else {
                    id = (int)(((unsigned)c0 ^ (o1 ? hy1 : hy0) ^ (o2 ? hz1 : hz0)) & 16383u);
                }
                id = valid ? id : 0;             // in-bounds LDS read
                w  = valid ? w  : 0.0f;          // zero contribution (== sentinel row)
                const float2 e = lds[id];
                a0 = fmaf(e.x, w, a0);
                a1 = fmaf(e.y, w, a1);
            }
            res[pp][l][0] = a0;
            res[pp][l][1] = a1;
        }
    }

    // ---- epilogue: LDS transpose (reuse table LDS) + coalesced nt stores ----
    vf4* __restrict__ l4 = (vf4*)lds_raw;                // 8192 float4 = 128 KB
    vf4* __restrict__ out4 = (vf4*)out;
    const long obase4 = (long)blockIdx.x * (CHUNK * 8);  // float4 per point = 8

#pragma unroll
    for (int pp = 0; pp < PPT; ++pp) {
        __syncthreads();                                 // LDS free (gathers/reads done)
        // write this thread's 32 floats as 8 rotated float4 groups (conflict-free)
#pragma unroll
        for (int g = 0; g < 8; ++g) {
            vf4 v;
            v.x = res[pp][2 * g][0];     v.y = res[pp][2 * g][1];
            v.z = res[pp][2 * g + 1][0]; v.w = res[pp][2 * g + 1][1];
            l4[t * 8 + ((g + t) & 7)] = v;
        }
        __syncthreads();
        // read back linear (conflict-free) and store lane-contiguous float4, nt
#pragma unroll
        for (int j = 0; j < 8; ++j) {
            const int i4 = j * 1024 + t;                 // linear float4 idx in tile
            const int q  = i4 >> 3;                      // local point
            const int g  = i4 & 7;                       // group
            const vf4 v = l4[q * 8 + ((g + q) & 7)];
            __builtin_nontemporal_store(v, &out4[obase4 + (long)pp * (TPB * 8) + i4]);
        }
    }
}

extern "C" void kernel_launch(void* const* d_in, const int* in_sizes, int n_in,
                              void* d_out, int out_size, void* d_ws, size_t ws_size,
                              hipStream_t stream) {
    const float* x   = (const float*)d_in[0];   // (B, 3) f32
    const float* emb = (const float*)d_in[1];   // (16, 16385, 2) f32
    float* out = (float*)d_out;                 // (B, 16, 2) f32

    const int nblocks = B_POINTS / CHUNK;       // 512
    hashenc_lds2<<<nblocks, TPB, 16384 * sizeof(float2), stream>>>(x, emb, out);
}